// Round 9
// baseline (627.740 us; speedup 1.0000x reference)
//
#include <hip/hip_runtime.h>

#define N_NODES 50000
#define E_EDGES 800000
#define D_OUT   64
#define COMB    144   // 64 + 64 + 16

typedef float  f32x4  __attribute__((ext_vector_type(4)));
typedef __bf16 bf16x8 __attribute__((ext_vector_type(8)));
typedef __bf16 bf16x4 __attribute__((ext_vector_type(4)));

// ---------------- workspace layout (bytes, 256-aligned) -------------------
// total 119,107,840 <= 122,308,096 proven available (round-5 guard passed)
#define WS_DEG     0           // int[N]        200,000
#define WS_START   200064      // int[N]        200,000
#define WS_CURSOR  400128      // int[N]        200,000
#define WS_WTS     600192      // bf16 wts      107,520
#define WS_PERM    707840      // int[E]      3,200,000  (sorted slot -> edge id)
#define WS_VMSG    3907840     // bf16[E][64] 102,400,000 (128B-aligned rows)
#define WS_EXMSG   106307840   // bf16[E][8]   12,800,000

#define BIG_ELEMS    (64*168)   // 10752
#define SMALL_ELEMS  (64*72)    // 4608

// ---------------------------------------------------------------------------
// prep: fp32 [K][64] weights -> bf16 transposed [64][Kpad] (zero pad)
// ---------------------------------------------------------------------------
__global__ __launch_bounds__(256) void prep_kernel(
    const float* __restrict__ kW0, const float* __restrict__ kW1, const float* __restrict__ kW2,
    const float* __restrict__ vW0, const float* __restrict__ vW1, const float* __restrict__ vW2,
    const float* __restrict__ oW0, const float* __restrict__ oW1, const float* __restrict__ oW2,
    __bf16* __restrict__ wout)
{
    const int b = blockIdx.x, tid = threadIdx.x;
    const float* src;
    __bf16* dst;
    int K, Kpad, lb;
    if (b < 42)      { src = kW0; dst = wout;             K = 144; Kpad = 168; lb = b; }
    else if (b < 84) { src = vW0; dst = wout + BIG_ELEMS; K = 144; Kpad = 168; lb = b - 42; }
    else {
        const int id = (b - 84) / 18; lb = (b - 84) % 18;
        const float* s7[7] = {kW1, kW2, vW1, vW2, oW0, oW1, oW2};
        src = s7[id]; dst = wout + 2 * BIG_ELEMS + id * SMALL_ELEMS;
        K = 64; Kpad = 72;
    }
    const int idx = lb * 256 + tid;
    const int col = idx / Kpad, k = idx % Kpad;
    dst[idx] = (k < K) ? (__bf16)src[k * 64 + col] : (__bf16)0.f;
}

// ---------------------------------------------------------------------------
// CSR pre-pass (consumed only by aggr): degree -> scan -> perm
// ---------------------------------------------------------------------------
__global__ __launch_bounds__(256) void deg_kernel(const int* __restrict__ edge_index,
                                                  int* __restrict__ deg)
{
    const int e = blockIdx.x * 256 + threadIdx.x;
    if (e < E_EDGES) atomicAdd(&deg[edge_index[E_EDGES + e]], 1);
}

__global__ __launch_bounds__(1024) void scan_kernel(const int* __restrict__ deg,
                                                    int* __restrict__ start,
                                                    int* __restrict__ cursor)
{
    __shared__ int wsum[16];
    __shared__ int carry_s;
    const int tid = threadIdx.x, lane = tid & 63, wv = tid >> 6;
    if (tid == 0) carry_s = 0;
    __syncthreads();
    for (int base = 0; base < N_NODES; base += 1024) {
        const int i = base + tid;
        const int v = (i < N_NODES) ? deg[i] : 0;
        int sc = v;
        #pragma unroll
        for (int off = 1; off < 64; off <<= 1) {
            int t = __shfl_up(sc, off);
            if (lane >= off) sc += t;
        }
        if (lane == 63) wsum[wv] = sc;
        const int c = carry_s;
        __syncthreads();
        if (wv == 0 && lane < 16) {
            int ws = wsum[lane];
            #pragma unroll
            for (int off = 1; off < 16; off <<= 1) {
                int t = __shfl_up(ws, off);
                if (lane >= off) ws += t;
            }
            wsum[lane] = ws;
        }
        __syncthreads();
        const int woff = (wv == 0) ? 0 : wsum[wv - 1];
        const int excl = c + woff + sc - v;
        if (i < N_NODES) { start[i] = excl; cursor[i] = excl; }
        __syncthreads();
        if (tid == 0) carry_s = c + wsum[15];
        __syncthreads();
    }
}

__global__ __launch_bounds__(256) void perm_kernel(const int* __restrict__ edge_index,
                                                   int* __restrict__ cursor,
                                                   int* __restrict__ perm)
{
    const int e = blockIdx.x * 256 + threadIdx.x;
    if (e < E_EDGES) {
        const int d = edge_index[E_EDGES + e];
        perm[atomicAdd(&cursor[d], 1)] = e;
    }
}

// ---------------------------------------------------------------------------
// MFMA fragment convention (both operands use the SAME contiguous k = hi*8+i
// placement, so any HW k-permutation cancels):
//   A: lane holds A[row=lane&15][k=(lane>>4)*8+i]
//   B: lane holds B[k=(lane>>4)*8+i][col=lane&15]  <- from Wt[col][k]
//   D: d[r] = D[row=(lane>>4)*4+r][col=lane&15]
// ---------------------------------------------------------------------------
__device__ __forceinline__ void gemm64(const __bf16* Arow, const __bf16* Wt,
                                       int hi, int row16, f32x4 acc[4])
{
    #pragma unroll
    for (int kc = 0; kc < 2; ++kc) {
        const bf16x8 a = *(const bf16x8*)(Arow + kc * 32 + hi * 8);
        #pragma unroll
        for (int n = 0; n < 4; ++n) {
            const bf16x8 bfr = *(const bf16x8*)(Wt + (n * 16 + row16) * 72 + kc * 32 + hi * 8);
            acc[n] = __builtin_amdgcn_mfma_f32_16x16x32_bf16(a, bfr, acc[n], 0, 0, 0);
        }
    }
}

__device__ __forceinline__ bf16x8 pack8(float4 a, float4 b) {
    bf16x8 r;
    r[0] = (__bf16)a.x; r[1] = (__bf16)a.y; r[2] = (__bf16)a.z; r[3] = (__bf16)a.w;
    r[4] = (__bf16)b.x; r[5] = (__bf16)b.y; r[6] = (__bf16)b.z; r[7] = (__bf16)b.w;
    return r;
}

// non-temporal bf16 store (nt = early-evict hint; still merges in L2)
__device__ __forceinline__ void nt_store_bf16(__bf16* p, float v) {
    __bf16 b = (__bf16)v;
    short s;
    __builtin_memcpy(&s, &b, 2);
    __builtin_nontemporal_store(s, reinterpret_cast<short*>(p));
}

// ===========================================================================
// Edge kernel: one wave per 16 edges in NATURAL order (round-7 structure,
// fastest measured), zero barriers, zero atomics. Messages split:
//   vmsg[e][64] = ex*v  (128B-aligned rows), exmsg[e][8] = ex per head.
// NT stores keep the 115MB stream from evicting x out of per-XCD L2.
// ===========================================================================
__global__ __launch_bounds__(256, 8) void edge_kernel(
    const float* __restrict__ x,
    const float* __restrict__ edge_attr,
    const int*   __restrict__ edge_index,
    const float* __restrict__ q,
    const float* __restrict__ kb0, const float* __restrict__ kb1, const float* __restrict__ kb2,
    const float* __restrict__ vb0, const float* __restrict__ vb1, const float* __restrict__ vb2,
    const __bf16* __restrict__ kW0t, const __bf16* __restrict__ kW1t, const __bf16* __restrict__ kW2t,
    const __bf16* __restrict__ vW0t, const __bf16* __restrict__ vW1t, const __bf16* __restrict__ vW2t,
    __bf16* __restrict__ vmsg, __bf16* __restrict__ exmsg)
{
    __shared__ __bf16 H_s[64][72];        // wave w uses rows w*16..w*16+15 only

    const int tid   = threadIdx.x;
    const int lane  = tid & 63;
    const int w     = tid >> 6;
    const int row16 = lane & 15;
    const int hi    = lane >> 4;
    const int wrow  = w * 16;

    const int e0 = (blockIdx.x * 4 + w) * 16;   // wave's 16 edges
    const int er = e0 + row16;                  // this lane's A-row edge

    const int src  = edge_index[er];
    const int dstn = edge_index[E_EDGES + er];

    // ---- L0 A-fragments: direct register gather (k = kc*32 + hi*8 + i) ----
    bf16x8 af[5];
    {
        const float* xs = &x[(size_t)src * 64 + hi * 8];
        af[0] = pack8(*(const float4*)xs,        *(const float4*)(xs + 4));
        af[1] = pack8(*(const float4*)(xs + 32), *(const float4*)(xs + 36));
        const float* xd = &x[(size_t)dstn * 64 + hi * 8];
        af[2] = pack8(*(const float4*)xd,        *(const float4*)(xd + 4));
        af[3] = pack8(*(const float4*)(xd + 32), *(const float4*)(xd + 36));
        if (hi < 2) {
            const float* ep = &edge_attr[(size_t)er * 16 + hi * 8];
            af[4] = pack8(*(const float4*)ep, *(const float4*)(ep + 4));
        } else {
            #pragma unroll
            for (int i = 0; i < 8; ++i) af[4][i] = (__bf16)0.f;
        }
    }

    const __bf16* hrow = &H_s[wrow + row16][0];
    float ex[4][4];

    // ================= K stack =================
    {
        f32x4 acc[4] = {{0,0,0,0},{0,0,0,0},{0,0,0,0},{0,0,0,0}};
        #pragma unroll
        for (int kc = 0; kc < 5; ++kc) {
            #pragma unroll
            for (int n = 0; n < 4; ++n) {
                const bf16x8 bfr = *(const bf16x8*)(kW0t + (n * 16 + row16) * 168 + kc * 32 + hi * 8);
                acc[n] = __builtin_amdgcn_mfma_f32_16x16x32_bf16(af[kc], bfr, acc[n], 0, 0, 0);
            }
        }
        float h0[4][4];
        #pragma unroll
        for (int n = 0; n < 4; ++n) {
            const float bias = kb0[n * 16 + row16];
            #pragma unroll
            for (int r = 0; r < 4; ++r) {
                h0[n][r] = fmaxf(acc[n][r] + bias, 0.f);
                H_s[wrow + hi * 4 + r][n * 16 + row16] = (__bf16)h0[n][r];
            }
        }
        __builtin_amdgcn_wave_barrier();

        f32x4 acc1[4] = {{0,0,0,0},{0,0,0,0},{0,0,0,0},{0,0,0,0}};
        gemm64(hrow, kW1t, hi, row16, acc1);
        float h1[4][4];
        #pragma unroll
        for (int n = 0; n < 4; ++n) {
            const float bias = kb1[n * 16 + row16];
            #pragma unroll
            for (int r = 0; r < 4; ++r) {
                h1[n][r] = fmaxf(h0[n][r] + acc1[n][r] + bias, 0.f);
                H_s[wrow + hi * 4 + r][n * 16 + row16] = (__bf16)h1[n][r];
            }
        }
        __builtin_amdgcn_wave_barrier();

        f32x4 acc2[4] = {{0,0,0,0},{0,0,0,0},{0,0,0,0},{0,0,0,0}};
        gemm64(hrow, kW2t, hi, row16, acc2);

        // scores: head = 2n + (row16>>3)
        #pragma unroll
        for (int n = 0; n < 4; ++n) {
            const float bias = kb2[n * 16 + row16];
            const float qv   = q[n * 16 + row16];
            #pragma unroll
            for (int r = 0; r < 4; ++r) {
                const float kk = h1[n][r] + acc2[n][r] + bias;
                float p2 = qv * kk;
                p2 += __shfl_xor(p2, 1);
                p2 += __shfl_xor(p2, 2);
                p2 += __shfl_xor(p2, 4);
                ex[n][r] = __expf(p2 * 0.35355339059327373f); // shift-free softmax: scores O(1)
            }
        }
    }

    // ================= V stack (af reused) =================
    float vv[4][4];
    {
        f32x4 acc[4] = {{0,0,0,0},{0,0,0,0},{0,0,0,0},{0,0,0,0}};
        #pragma unroll
        for (int kc = 0; kc < 5; ++kc) {
            #pragma unroll
            for (int n = 0; n < 4; ++n) {
                const bf16x8 bfr = *(const bf16x8*)(vW0t + (n * 16 + row16) * 168 + kc * 32 + hi * 8);
                acc[n] = __builtin_amdgcn_mfma_f32_16x16x32_bf16(af[kc], bfr, acc[n], 0, 0, 0);
            }
        }
        float h0[4][4];
        #pragma unroll
        for (int n = 0; n < 4; ++n) {
            const float bias = vb0[n * 16 + row16];
            #pragma unroll
            for (int r = 0; r < 4; ++r) {
                h0[n][r] = fmaxf(acc[n][r] + bias, 0.f);
                H_s[wrow + hi * 4 + r][n * 16 + row16] = (__bf16)h0[n][r];
            }
        }
        __builtin_amdgcn_wave_barrier();

        f32x4 acc1[4] = {{0,0,0,0},{0,0,0,0},{0,0,0,0},{0,0,0,0}};
        gemm64(hrow, vW1t, hi, row16, acc1);
        float h1[4][4];
        #pragma unroll
        for (int n = 0; n < 4; ++n) {
            const float bias = vb1[n * 16 + row16];
            #pragma unroll
            for (int r = 0; r < 4; ++r) {
                h1[n][r] = fmaxf(h0[n][r] + acc1[n][r] + bias, 0.f);
                H_s[wrow + hi * 4 + r][n * 16 + row16] = (__bf16)h1[n][r];
            }
        }
        __builtin_amdgcn_wave_barrier();

        f32x4 acc2[4] = {{0,0,0,0},{0,0,0,0},{0,0,0,0},{0,0,0,0}};
        gemm64(hrow, vW2t, hi, row16, acc2);
        #pragma unroll
        for (int n = 0; n < 4; ++n) {
            const float bias = vb2[n * 16 + row16];
            #pragma unroll
            for (int r = 0; r < 4; ++r)
                vv[n][r] = h1[n][r] + acc2[n][r] + bias;
        }
    }

    // ====== message store: natural slot, sequential, NT-hinted ======
    #pragma unroll
    for (int r = 0; r < 4; ++r) {
        const int erow = e0 + hi * 4 + r;
        __bf16* mrow = vmsg + (size_t)erow * 64;
        #pragma unroll
        for (int n = 0; n < 4; ++n)
            nt_store_bf16(mrow + n * 16 + row16, ex[n][r] * vv[n][r]);
        if ((row16 & 7) == 0) {                      // row16 in {0,8}
            __bf16* erow8 = exmsg + (size_t)erow * 8;
            #pragma unroll
            for (int n = 0; n < 4; ++n)
                nt_store_bf16(erow8 + 2 * n + (row16 >> 3), ex[n][r]);
        }
    }
}

// ---------------------------------------------------------------------------
// Aggregation: wave per node, 4 edges/iter via 4x16-lane groups.
// Lane (g,l): loads bf16x4 of channels l*4..l*4+3 (head l/2) from its
// group's edge row; group partials combined by 2 shfl_xor; lanes g==0
// write float4. Aligned 128B rows -> no line-split amplification.
// ---------------------------------------------------------------------------
__global__ __launch_bounds__(256, 8) void aggr_kernel(
    const int* __restrict__ start, const int* __restrict__ endc,
    const int* __restrict__ perm,
    const __bf16* __restrict__ vmsg, const __bf16* __restrict__ exmsg,
    float* __restrict__ aggr_out)
{
    const int lane = threadIdx.x & 63;
    const int n    = blockIdx.x * 4 + (threadIdx.x >> 6);
    if (n >= N_NODES) return;
    const int g = lane >> 4;          // edge-group 0..3
    const int l = lane & 15;          // lane within group (channel slice l*4..)
    const int s0 = start[n], e1 = endc[n];   // cursor-after-perm == start[n+1]

    float m0 = 0.f, m1 = 0.f, m2 = 0.f, m3 = 0.f, ae = 0.f;
    for (int i = s0 + g; i < e1; i += 4) {
        const int pe = perm[i];
        const bf16x4 v = *(const bf16x4*)&vmsg[(size_t)pe * 64 + l * 4];
        ae += (float)exmsg[(size_t)pe * 8 + (l >> 1)];
        m0 += (float)v[0]; m1 += (float)v[1]; m2 += (float)v[2]; m3 += (float)v[3];
    }
    #pragma unroll
    for (int m = 16; m < 64; m <<= 1) {
        m0 += __shfl_xor(m0, m); m1 += __shfl_xor(m1, m);
        m2 += __shfl_xor(m2, m); m3 += __shfl_xor(m3, m);
        ae += __shfl_xor(ae, m);
    }
    if (g == 0) {
        const float inv = (ae > 0.f) ? 1.f / ae : 0.f;
        float4 o;
        o.x = fmaxf(m0 * inv, 0.f);
        o.y = fmaxf(m1 * inv, 0.f);
        o.z = fmaxf(m2 * inv, 0.f);
        o.w = fmaxf(m3 * inv, 0.f);
        *(float4*)&aggr_out[(size_t)n * 64 + l * 4] = o;
    }
}

// ---------------------------------------------------------------------------
// Node kernel: stages f32 aggr (from d_out scratch) into LDS, runs out
// stack, overwrites d_out with the final result. Per-block read==write rows.
// ---------------------------------------------------------------------------
__global__ __launch_bounds__(256) void node_kernel(
    const float* __restrict__ x, const float* __restrict__ aggr_in,
    const float* __restrict__ ob0, const float* __restrict__ ob1, const float* __restrict__ ob2,
    const __bf16* __restrict__ oW0t, const __bf16* __restrict__ oW1t, const __bf16* __restrict__ oW2t,
    float* __restrict__ out)
{
    __shared__ __bf16 A_s[64][72];
    __shared__ __bf16 H_s[64][72];

    const int tid  = threadIdx.x;
    const int lane = tid & 63;
    const int w    = tid >> 6;
    const int n0   = blockIdx.x * 64;
    const int row16 = lane & 15;
    const int hi    = lane >> 4;

    {   // stage aggr rows (f32 -> bf16)
        const int r = tid >> 2, seg = tid & 3;       // 64 rows x 4 segs x 16
        const int node = n0 + r;
        #pragma unroll
        for (int gg = 0; gg < 4; ++gg) {
            bf16x4 h; h[0] = h[1] = h[2] = h[3] = (__bf16)0.f;
            if (node < N_NODES) {
                const float4 f = *(const float4*)&aggr_in[(size_t)node * 64 + seg * 16 + gg * 4];
                h[0] = (__bf16)f.x; h[1] = (__bf16)f.y; h[2] = (__bf16)f.z; h[3] = (__bf16)f.w;
            }
            *(bf16x4*)&A_s[r][seg * 16 + gg * 4] = h;
        }
    }
    __syncthreads();

    const __bf16* arow = &A_s[w * 16 + row16][0];
    const __bf16* hrow = &H_s[w * 16 + row16][0];

    f32x4 acc[4] = {{0,0,0,0},{0,0,0,0},{0,0,0,0},{0,0,0,0}};
    gemm64(arow, oW0t, hi, row16, acc);
    float h0[4][4];
    #pragma unroll
    for (int n = 0; n < 4; ++n) {
        const float bias = ob0[n * 16 + row16];
        #pragma unroll
        for (int r = 0; r < 4; ++r) {
            h0[n][r] = fmaxf(acc[n][r] + bias, 0.f);
            H_s[w * 16 + hi * 4 + r][n * 16 + row16] = (__bf16)h0[n][r];
        }
    }
    __builtin_amdgcn_wave_barrier();

    f32x4 acc1[4] = {{0,0,0,0},{0,0,0,0},{0,0,0,0},{0,0,0,0}};
    gemm64(hrow, oW1t, hi, row16, acc1);
    float h1[4][4];
    #pragma unroll
    for (int n = 0; n < 4; ++n) {
        const float bias = ob1[n * 16 + row16];
        #pragma unroll
        for (int r = 0; r < 4; ++r) {
            h1[n][r] = fmaxf(h0[n][r] + acc1[n][r] + bias, 0.f);
            H_s[w * 16 + hi * 4 + r][n * 16 + row16] = (__bf16)h1[n][r];
        }
    }
    __builtin_amdgcn_wave_barrier();

    f32x4 acc2[4] = {{0,0,0,0},{0,0,0,0},{0,0,0,0},{0,0,0,0}};
    gemm64(hrow, oW2t, hi, row16, acc2);
    #pragma unroll
    for (int n = 0; n < 4; ++n) {
        const float bias = ob2[n * 16 + row16];
        #pragma unroll
        for (int r = 0; r < 4; ++r) {
            const int node = n0 + w * 16 + hi * 4 + r;
            if (node < N_NODES) {
                const int col = n * 16 + row16;
                const float o = h1[n][r] + acc2[n][r] + bias;
                out[(size_t)node * 64 + col] = fmaxf(x[(size_t)node * 64 + col] + o, 0.f);
            }
        }
    }
}

extern "C" void kernel_launch(void* const* d_in, const int* in_sizes, int n_in,
                              void* d_out, int out_size, void* d_ws, size_t ws_size,
                              hipStream_t stream) {
    const float* x  = (const float*)d_in[0];
    const float* ea = (const float*)d_in[1];
    const int*   ei = (const int*)d_in[2];
    const float* q  = (const float*)d_in[3];
    const float* kW0 = (const float*)d_in[4];  const float* kb0 = (const float*)d_in[5];
    const float* kW1 = (const float*)d_in[6];  const float* kb1 = (const float*)d_in[7];
    const float* kW2 = (const float*)d_in[8];  const float* kb2 = (const float*)d_in[9];
    const float* vW0 = (const float*)d_in[10]; const float* vb0 = (const float*)d_in[11];
    const float* vW1 = (const float*)d_in[12]; const float* vb1 = (const float*)d_in[13];
    const float* vW2 = (const float*)d_in[14]; const float* vb2 = (const float*)d_in[15];
    const float* oW0 = (const float*)d_in[16]; const float* ob0 = (const float*)d_in[17];
    const float* oW1 = (const float*)d_in[18]; const float* ob1 = (const float*)d_in[19];
    const float* oW2 = (const float*)d_in[20]; const float* ob2 = (const float*)d_in[21];

    char* ws = (char*)d_ws;
    int*    deg    = (int*)(ws + WS_DEG);
    int*    start  = (int*)(ws + WS_START);
    int*    cursor = (int*)(ws + WS_CURSOR);
    __bf16* wts    = (__bf16*)(ws + WS_WTS);
    int*    perm   = (int*)(ws + WS_PERM);
    __bf16* vmsg   = (__bf16*)(ws + WS_VMSG);
    __bf16* exmsg  = (__bf16*)(ws + WS_EXMSG);
    float*  aggrf  = (float*)d_out;              // d_out doubles as scratch

    __bf16* kW0t = wts;
    __bf16* vW0t = wts + BIG_ELEMS;
    __bf16* sm   = wts + 2 * BIG_ELEMS;
    __bf16* kW1t = sm;                   __bf16* kW2t = sm + SMALL_ELEMS;
    __bf16* vW1t = sm + 2 * SMALL_ELEMS; __bf16* vW2t = sm + 3 * SMALL_ELEMS;
    __bf16* oW0t = sm + 4 * SMALL_ELEMS; __bf16* oW1t = sm + 5 * SMALL_ELEMS;
    __bf16* oW2t = sm + 6 * SMALL_ELEMS;

    hipMemsetAsync(deg, 0, (size_t)N_NODES * sizeof(int), stream);

    // CSR pre-pass (consumed only by aggr_kernel)
    deg_kernel<<<E_EDGES / 256, 256, 0, stream>>>(ei, deg);
    scan_kernel<<<1, 1024, 0, stream>>>(deg, start, cursor);
    perm_kernel<<<E_EDGES / 256, 256, 0, stream>>>(ei, cursor, perm);

    prep_kernel<<<210, 256, 0, stream>>>(kW0, kW1, kW2, vW0, vW1, vW2, oW0, oW1, oW2, wts);

    edge_kernel<<<E_EDGES / 64, 256, 0, stream>>>(
        x, ea, ei, q,
        kb0, kb1, kb2, vb0, vb1, vb2,
        kW0t, kW1t, kW2t, vW0t, vW1t, vW2t,
        vmsg, exmsg);

    aggr_kernel<<<(N_NODES + 3) / 4, 256, 0, stream>>>(start, cursor, perm, vmsg, exmsg, aggrf);

    node_kernel<<<(N_NODES + 63) / 64, 256, 0, stream>>>(
        x, aggrf, ob0, ob1, ob2, oW0t, oW1t, oW2t, (float*)d_out);
}

// Round 10
// 623.996 us; speedup vs baseline: 1.0060x; 1.0060x over previous
//
#include <hip/hip_runtime.h>

#define N_NODES 50000
#define E_EDGES 800000
#define D_OUT   64
#define COMB    144   // 64 + 64 + 16

typedef float  f32x4  __attribute__((ext_vector_type(4)));
typedef __bf16 bf16x8 __attribute__((ext_vector_type(8)));
typedef __bf16 bf16x4 __attribute__((ext_vector_type(4)));

// ---------------- workspace layout (bytes, 256-aligned) -------------------
// total 119,107,840 <= 122,308,096 proven available (round-5 guard passed)
#define WS_DEG     0           // int[N]        200,000
#define WS_START   200064      // int[N]        200,000
#define WS_CURSOR  400128      // int[N]        200,000
#define WS_WTS     600192      // bf16 wts      107,520
#define WS_PERM    707840      // int[E]      3,200,000  (sorted slot -> edge id)
#define WS_VMSG    3907840     // bf16[E][64] 102,400,000 (128B-aligned rows)
#define WS_EXMSG   106307840   // bf16[E][8]   12,800,000

#define BIG_ELEMS    (64*168)   // 10752
#define SMALL_ELEMS  (64*72)    // 4608

// ---------------------------------------------------------------------------
// prep: fp32 [K][64] weights -> bf16 transposed [64][Kpad] (zero pad)
// ---------------------------------------------------------------------------
__global__ __launch_bounds__(256) void prep_kernel(
    const float* __restrict__ kW0, const float* __restrict__ kW1, const float* __restrict__ kW2,
    const float* __restrict__ vW0, const float* __restrict__ vW1, const float* __restrict__ vW2,
    const float* __restrict__ oW0, const float* __restrict__ oW1, const float* __restrict__ oW2,
    __bf16* __restrict__ wout)
{
    const int b = blockIdx.x, tid = threadIdx.x;
    const float* src;
    __bf16* dst;
    int K, Kpad, lb;
    if (b < 42)      { src = kW0; dst = wout;             K = 144; Kpad = 168; lb = b; }
    else if (b < 84) { src = vW0; dst = wout + BIG_ELEMS; K = 144; Kpad = 168; lb = b - 42; }
    else {
        const int id = (b - 84) / 18; lb = (b - 84) % 18;
        const float* s7[7] = {kW1, kW2, vW1, vW2, oW0, oW1, oW2};
        src = s7[id]; dst = wout + 2 * BIG_ELEMS + id * SMALL_ELEMS;
        K = 64; Kpad = 72;
    }
    const int idx = lb * 256 + tid;
    const int col = idx / Kpad, k = idx % Kpad;
    dst[idx] = (k < K) ? (__bf16)src[k * 64 + col] : (__bf16)0.f;
}

// ---------------------------------------------------------------------------
// CSR pre-pass (consumed only by aggr): degree -> scan -> perm
// ---------------------------------------------------------------------------
__global__ __launch_bounds__(256) void deg_kernel(const int* __restrict__ edge_index,
                                                  int* __restrict__ deg)
{
    const int e = blockIdx.x * 256 + threadIdx.x;
    if (e < E_EDGES) atomicAdd(&deg[edge_index[E_EDGES + e]], 1);
}

__global__ __launch_bounds__(1024) void scan_kernel(const int* __restrict__ deg,
                                                    int* __restrict__ start,
                                                    int* __restrict__ cursor)
{
    __shared__ int wsum[16];
    __shared__ int carry_s;
    const int tid = threadIdx.x, lane = tid & 63, wv = tid >> 6;
    if (tid == 0) carry_s = 0;
    __syncthreads();
    for (int base = 0; base < N_NODES; base += 1024) {
        const int i = base + tid;
        const int v = (i < N_NODES) ? deg[i] : 0;
        int sc = v;
        #pragma unroll
        for (int off = 1; off < 64; off <<= 1) {
            int t = __shfl_up(sc, off);
            if (lane >= off) sc += t;
        }
        if (lane == 63) wsum[wv] = sc;
        const int c = carry_s;
        __syncthreads();
        if (wv == 0 && lane < 16) {
            int ws = wsum[lane];
            #pragma unroll
            for (int off = 1; off < 16; off <<= 1) {
                int t = __shfl_up(ws, off);
                if (lane >= off) ws += t;
            }
            wsum[lane] = ws;
        }
        __syncthreads();
        const int woff = (wv == 0) ? 0 : wsum[wv - 1];
        const int excl = c + woff + sc - v;
        if (i < N_NODES) { start[i] = excl; cursor[i] = excl; }
        __syncthreads();
        if (tid == 0) carry_s = c + wsum[15];
        __syncthreads();
    }
}

__global__ __launch_bounds__(256) void perm_kernel(const int* __restrict__ edge_index,
                                                   int* __restrict__ cursor,
                                                   int* __restrict__ perm)
{
    const int e = blockIdx.x * 256 + threadIdx.x;
    if (e < E_EDGES) {
        const int d = edge_index[E_EDGES + e];
        perm[atomicAdd(&cursor[d], 1)] = e;
    }
}

// ---------------------------------------------------------------------------
// MFMA fragment convention (both operands use the SAME contiguous k = hi*8+i
// placement, so any HW k-permutation cancels):
//   A: lane holds A[row=lane&15][k=(lane>>4)*8+i]
//   B: lane holds B[k=(lane>>4)*8+i][col=lane&15]  <- from Wt[col][k]
//   D: d[r] = D[row=(lane>>4)*4+r][col=lane&15]
// ---------------------------------------------------------------------------
__device__ __forceinline__ void gemm64(const __bf16* Arow, const __bf16* Wt,
                                       int hi, int row16, f32x4 acc[4])
{
    #pragma unroll
    for (int kc = 0; kc < 2; ++kc) {
        const bf16x8 a = *(const bf16x8*)(Arow + kc * 32 + hi * 8);
        #pragma unroll
        for (int n = 0; n < 4; ++n) {
            const bf16x8 bfr = *(const bf16x8*)(Wt + (n * 16 + row16) * 72 + kc * 32 + hi * 8);
            acc[n] = __builtin_amdgcn_mfma_f32_16x16x32_bf16(a, bfr, acc[n], 0, 0, 0);
        }
    }
}

__device__ __forceinline__ bf16x8 pack8(float4 a, float4 b) {
    bf16x8 r;
    r[0] = (__bf16)a.x; r[1] = (__bf16)a.y; r[2] = (__bf16)a.z; r[3] = (__bf16)a.w;
    r[4] = (__bf16)b.x; r[5] = (__bf16)b.y; r[6] = (__bf16)b.z; r[7] = (__bf16)b.w;
    return r;
}

// ===========================================================================
// Edge kernel: one wave per 16 edges in NATURAL order (round-7 structure,
// fastest measured), zero barriers, zero atomics, PLAIN stores (L2 merges
// partial-line writes; NT was a 3x write-amplification regression in r9).
// Messages split: vmsg[e][64] = ex*v (128B-aligned), exmsg[e][8] = ex/head.
// ===========================================================================
__global__ __launch_bounds__(256, 8) void edge_kernel(
    const float* __restrict__ x,
    const float* __restrict__ edge_attr,
    const int*   __restrict__ edge_index,
    const float* __restrict__ q,
    const float* __restrict__ kb0, const float* __restrict__ kb1, const float* __restrict__ kb2,
    const float* __restrict__ vb0, const float* __restrict__ vb1, const float* __restrict__ vb2,
    const __bf16* __restrict__ kW0t, const __bf16* __restrict__ kW1t, const __bf16* __restrict__ kW2t,
    const __bf16* __restrict__ vW0t, const __bf16* __restrict__ vW1t, const __bf16* __restrict__ vW2t,
    __bf16* __restrict__ vmsg, __bf16* __restrict__ exmsg)
{
    __shared__ __bf16 H_s[64][72];        // wave w uses rows w*16..w*16+15 only

    const int tid   = threadIdx.x;
    const int lane  = tid & 63;
    const int w     = tid >> 6;
    const int row16 = lane & 15;
    const int hi    = lane >> 4;
    const int wrow  = w * 16;

    const int e0 = (blockIdx.x * 4 + w) * 16;   // wave's 16 edges
    const int er = e0 + row16;                  // this lane's A-row edge

    const int src  = edge_index[er];
    const int dstn = edge_index[E_EDGES + er];

    // ---- L0 A-fragments: direct register gather (k = kc*32 + hi*8 + i) ----
    bf16x8 af[5];
    {
        const float* xs = &x[(size_t)src * 64 + hi * 8];
        af[0] = pack8(*(const float4*)xs,        *(const float4*)(xs + 4));
        af[1] = pack8(*(const float4*)(xs + 32), *(const float4*)(xs + 36));
        const float* xd = &x[(size_t)dstn * 64 + hi * 8];
        af[2] = pack8(*(const float4*)xd,        *(const float4*)(xd + 4));
        af[3] = pack8(*(const float4*)(xd + 32), *(const float4*)(xd + 36));
        if (hi < 2) {
            const float* ep = &edge_attr[(size_t)er * 16 + hi * 8];
            af[4] = pack8(*(const float4*)ep, *(const float4*)(ep + 4));
        } else {
            #pragma unroll
            for (int i = 0; i < 8; ++i) af[4][i] = (__bf16)0.f;
        }
    }

    const __bf16* hrow = &H_s[wrow + row16][0];
    float ex[4][4];

    // ================= K stack =================
    {
        f32x4 acc[4] = {{0,0,0,0},{0,0,0,0},{0,0,0,0},{0,0,0,0}};
        #pragma unroll
        for (int kc = 0; kc < 5; ++kc) {
            #pragma unroll
            for (int n = 0; n < 4; ++n) {
                const bf16x8 bfr = *(const bf16x8*)(kW0t + (n * 16 + row16) * 168 + kc * 32 + hi * 8);
                acc[n] = __builtin_amdgcn_mfma_f32_16x16x32_bf16(af[kc], bfr, acc[n], 0, 0, 0);
            }
        }
        float h0[4][4];
        #pragma unroll
        for (int n = 0; n < 4; ++n) {
            const float bias = kb0[n * 16 + row16];
            #pragma unroll
            for (int r = 0; r < 4; ++r) {
                h0[n][r] = fmaxf(acc[n][r] + bias, 0.f);
                H_s[wrow + hi * 4 + r][n * 16 + row16] = (__bf16)h0[n][r];
            }
        }
        __builtin_amdgcn_wave_barrier();

        f32x4 acc1[4] = {{0,0,0,0},{0,0,0,0},{0,0,0,0},{0,0,0,0}};
        gemm64(hrow, kW1t, hi, row16, acc1);
        float h1[4][4];
        #pragma unroll
        for (int n = 0; n < 4; ++n) {
            const float bias = kb1[n * 16 + row16];
            #pragma unroll
            for (int r = 0; r < 4; ++r) {
                h1[n][r] = fmaxf(h0[n][r] + acc1[n][r] + bias, 0.f);
                H_s[wrow + hi * 4 + r][n * 16 + row16] = (__bf16)h1[n][r];
            }
        }
        __builtin_amdgcn_wave_barrier();

        f32x4 acc2[4] = {{0,0,0,0},{0,0,0,0},{0,0,0,0},{0,0,0,0}};
        gemm64(hrow, kW2t, hi, row16, acc2);

        // scores: head = 2n + (row16>>3)
        #pragma unroll
        for (int n = 0; n < 4; ++n) {
            const float bias = kb2[n * 16 + row16];
            const float qv   = q[n * 16 + row16];
            #pragma unroll
            for (int r = 0; r < 4; ++r) {
                const float kk = h1[n][r] + acc2[n][r] + bias;
                float p2 = qv * kk;
                p2 += __shfl_xor(p2, 1);
                p2 += __shfl_xor(p2, 2);
                p2 += __shfl_xor(p2, 4);
                ex[n][r] = __expf(p2 * 0.35355339059327373f); // shift-free softmax: scores O(1)
            }
        }
    }

    // ================= V stack (af reused) =================
    float vv[4][4];
    {
        f32x4 acc[4] = {{0,0,0,0},{0,0,0,0},{0,0,0,0},{0,0,0,0}};
        #pragma unroll
        for (int kc = 0; kc < 5; ++kc) {
            #pragma unroll
            for (int n = 0; n < 4; ++n) {
                const bf16x8 bfr = *(const bf16x8*)(vW0t + (n * 16 + row16) * 168 + kc * 32 + hi * 8);
                acc[n] = __builtin_amdgcn_mfma_f32_16x16x32_bf16(af[kc], bfr, acc[n], 0, 0, 0);
            }
        }
        float h0[4][4];
        #pragma unroll
        for (int n = 0; n < 4; ++n) {
            const float bias = vb0[n * 16 + row16];
            #pragma unroll
            for (int r = 0; r < 4; ++r) {
                h0[n][r] = fmaxf(acc[n][r] + bias, 0.f);
                H_s[wrow + hi * 4 + r][n * 16 + row16] = (__bf16)h0[n][r];
            }
        }
        __builtin_amdgcn_wave_barrier();

        f32x4 acc1[4] = {{0,0,0,0},{0,0,0,0},{0,0,0,0},{0,0,0,0}};
        gemm64(hrow, vW1t, hi, row16, acc1);
        float h1[4][4];
        #pragma unroll
        for (int n = 0; n < 4; ++n) {
            const float bias = vb1[n * 16 + row16];
            #pragma unroll
            for (int r = 0; r < 4; ++r) {
                h1[n][r] = fmaxf(h0[n][r] + acc1[n][r] + bias, 0.f);
                H_s[wrow + hi * 4 + r][n * 16 + row16] = (__bf16)h1[n][r];
            }
        }
        __builtin_amdgcn_wave_barrier();

        f32x4 acc2[4] = {{0,0,0,0},{0,0,0,0},{0,0,0,0},{0,0,0,0}};
        gemm64(hrow, vW2t, hi, row16, acc2);
        #pragma unroll
        for (int n = 0; n < 4; ++n) {
            const float bias = vb2[n * 16 + row16];
            #pragma unroll
            for (int r = 0; r < 4; ++r)
                vv[n][r] = h1[n][r] + acc2[n][r] + bias;
        }
    }

    // ====== message store: natural slot, sequential, PLAIN stores ======
    #pragma unroll
    for (int r = 0; r < 4; ++r) {
        const int erow = e0 + hi * 4 + r;
        __bf16* mrow = vmsg + (size_t)erow * 64;
        #pragma unroll
        for (int n = 0; n < 4; ++n)
            mrow[n * 16 + row16] = (__bf16)(ex[n][r] * vv[n][r]);
        if ((row16 & 7) == 0) {                      // row16 in {0,8}
            __bf16* erow8 = exmsg + (size_t)erow * 8;
            #pragma unroll
            for (int n = 0; n < 4; ++n)
                erow8[2 * n + (row16 >> 3)] = (__bf16)ex[n][r];
        }
    }
}

// ---------------------------------------------------------------------------
// Aggregation: wave per node, 4 edges/iter via 4x16-lane groups.
// Lane (g,l): loads bf16x4 of channels l*4..l*4+3 (head l/2) from its
// group's edge row; group partials combined by 2 shfl_xor; lanes g==0
// write float4. Aligned 128B rows -> no line-split amplification.
// ---------------------------------------------------------------------------
__global__ __launch_bounds__(256, 8) void aggr_kernel(
    const int* __restrict__ start, const int* __restrict__ endc,
    const int* __restrict__ perm,
    const __bf16* __restrict__ vmsg, const __bf16* __restrict__ exmsg,
    float* __restrict__ aggr_out)
{
    const int lane = threadIdx.x & 63;
    const int n    = blockIdx.x * 4 + (threadIdx.x >> 6);
    if (n >= N_NODES) return;
    const int g = lane >> 4;          // edge-group 0..3
    const int l = lane & 15;          // lane within group (channel slice l*4..)
    const int s0 = start[n], e1 = endc[n];   // cursor-after-perm == start[n+1]

    float m0 = 0.f, m1 = 0.f, m2 = 0.f, m3 = 0.f, ae = 0.f;
    for (int i = s0 + g; i < e1; i += 4) {
        const int pe = perm[i];
        const bf16x4 v = *(const bf16x4*)&vmsg[(size_t)pe * 64 + l * 4];
        ae += (float)exmsg[(size_t)pe * 8 + (l >> 1)];
        m0 += (float)v[0]; m1 += (float)v[1]; m2 += (float)v[2]; m3 += (float)v[3];
    }
    #pragma unroll
    for (int m = 16; m < 64; m <<= 1) {
        m0 += __shfl_xor(m0, m); m1 += __shfl_xor(m1, m);
        m2 += __shfl_xor(m2, m); m3 += __shfl_xor(m3, m);
        ae += __shfl_xor(ae, m);
    }
    if (g == 0) {
        const float inv = (ae > 0.f) ? 1.f / ae : 0.f;
        float4 o;
        o.x = fmaxf(m0 * inv, 0.f);
        o.y = fmaxf(m1 * inv, 0.f);
        o.z = fmaxf(m2 * inv, 0.f);
        o.w = fmaxf(m3 * inv, 0.f);
        *(float4*)&aggr_out[(size_t)n * 64 + l * 4] = o;
    }
}

// ---------------------------------------------------------------------------
// Node kernel: stages f32 aggr (from d_out scratch) into LDS, runs out
// stack, overwrites d_out with the final result. Per-block read==write rows.
// ---------------------------------------------------------------------------
__global__ __launch_bounds__(256) void node_kernel(
    const float* __restrict__ x, const float* __restrict__ aggr_in,
    const float* __restrict__ ob0, const float* __restrict__ ob1, const float* __restrict__ ob2,
    const __bf16* __restrict__ oW0t, const __bf16* __restrict__ oW1t, const __bf16* __restrict__ oW2t,
    float* __restrict__ out)
{
    __shared__ __bf16 A_s[64][72];
    __shared__ __bf16 H_s[64][72];

    const int tid  = threadIdx.x;
    const int lane = tid & 63;
    const int w    = tid >> 6;
    const int n0   = blockIdx.x * 64;
    const int row16 = lane & 15;
    const int hi    = lane >> 4;

    {   // stage aggr rows (f32 -> bf16)
        const int r = tid >> 2, seg = tid & 3;       // 64 rows x 4 segs x 16
        const int node = n0 + r;
        #pragma unroll
        for (int gg = 0; gg < 4; ++gg) {
            bf16x4 h; h[0] = h[1] = h[2] = h[3] = (__bf16)0.f;
            if (node < N_NODES) {
                const float4 f = *(const float4*)&aggr_in[(size_t)node * 64 + seg * 16 + gg * 4];
                h[0] = (__bf16)f.x; h[1] = (__bf16)f.y; h[2] = (__bf16)f.z; h[3] = (__bf16)f.w;
            }
            *(bf16x4*)&A_s[r][seg * 16 + gg * 4] = h;
        }
    }
    __syncthreads();

    const __bf16* arow = &A_s[w * 16 + row16][0];
    const __bf16* hrow = &H_s[w * 16 + row16][0];

    f32x4 acc[4] = {{0,0,0,0},{0,0,0,0},{0,0,0,0},{0,0,0,0}};
    gemm64(arow, oW0t, hi, row16, acc);
    float h0[4][4];
    #pragma unroll
    for (int n = 0; n < 4; ++n) {
        const float bias = ob0[n * 16 + row16];
        #pragma unroll
        for (int r = 0; r < 4; ++r) {
            h0[n][r] = fmaxf(acc[n][r] + bias, 0.f);
            H_s[w * 16 + hi * 4 + r][n * 16 + row16] = (__bf16)h0[n][r];
        }
    }
    __builtin_amdgcn_wave_barrier();

    f32x4 acc1[4] = {{0,0,0,0},{0,0,0,0},{0,0,0,0},{0,0,0,0}};
    gemm64(hrow, oW1t, hi, row16, acc1);
    float h1[4][4];
    #pragma unroll
    for (int n = 0; n < 4; ++n) {
        const float bias = ob1[n * 16 + row16];
        #pragma unroll
        for (int r = 0; r < 4; ++r) {
            h1[n][r] = fmaxf(h0[n][r] + acc1[n][r] + bias, 0.f);
            H_s[w * 16 + hi * 4 + r][n * 16 + row16] = (__bf16)h1[n][r];
        }
    }
    __builtin_amdgcn_wave_barrier();

    f32x4 acc2[4] = {{0,0,0,0},{0,0,0,0},{0,0,0,0},{0,0,0,0}};
    gemm64(hrow, oW2t, hi, row16, acc2);
    #pragma unroll
    for (int n = 0; n < 4; ++n) {
        const float bias = ob2[n * 16 + row16];
        #pragma unroll
        for (int r = 0; r < 4; ++r) {
            const int node = n0 + w * 16 + hi * 4 + r;
            if (node < N_NODES) {
                const int col = n * 16 + row16;
                const float o = h1[n][r] + acc2[n][r] + bias;
                out[(size_t)node * 64 + col] = fmaxf(x[(size_t)node * 64 + col] + o, 0.f);
            }
        }
    }
}

extern "C" void kernel_launch(void* const* d_in, const int* in_sizes, int n_in,
                              void* d_out, int out_size, void* d_ws, size_t ws_size,
                              hipStream_t stream) {
    const float* x  = (const float*)d_in[0];
    const float* ea = (const float*)d_in[1];
    const int*   ei = (const int*)d_in[2];
    const float* q  = (const float*)d_in[3];
    const float* kW0 = (const float*)d_in[4];  const float* kb0 = (const float*)d_in[5];
    const float* kW1 = (const float*)d_in[6];  const float* kb1 = (const float*)d_in[7];
    const float* kW2 = (const float*)d_in[8];  const float* kb2 = (const float*)d_in[9];
    const float* vW0 = (const float*)d_in[10]; const float* vb0 = (const float*)d_in[11];
    const float* vW1 = (const float*)d_in[12]; const float* vb1 = (const float*)d_in[13];
    const float* vW2 = (const float*)d_in[14]; const float* vb2 = (const float*)d_in[15];
    const float* oW0 = (const float*)d_in[16]; const float* ob0 = (const float*)d_in[17];
    const float* oW1 = (const float*)d_in[18]; const float* ob1 = (const float*)d_in[19];
    const float* oW2 = (const float*)d_in[20]; const float* ob2 = (const float*)d_in[21];

    char* ws = (char*)d_ws;
    int*    deg    = (int*)(ws + WS_DEG);
    int*    start  = (int*)(ws + WS_START);
    int*    cursor = (int*)(ws + WS_CURSOR);
    __bf16* wts    = (__bf16*)(ws + WS_WTS);
    int*    perm   = (int*)(ws + WS_PERM);
    __bf16* vmsg   = (__bf16*)(ws + WS_VMSG);
    __bf16* exmsg  = (__bf16*)(ws + WS_EXMSG);
    float*  aggrf  = (float*)d_out;              // d_out doubles as scratch

    __bf16* kW0t = wts;
    __bf16* vW0t = wts + BIG_ELEMS;
    __bf16* sm   = wts + 2 * BIG_ELEMS;
    __bf16* kW1t = sm;                   __bf16* kW2t = sm + SMALL_ELEMS;
    __bf16* vW1t = sm + 2 * SMALL_ELEMS; __bf16* vW2t = sm + 3 * SMALL_ELEMS;
    __bf16* oW0t = sm + 4 * SMALL_ELEMS; __bf16* oW1t = sm + 5 * SMALL_ELEMS;
    __bf16* oW2t = sm + 6 * SMALL_ELEMS;

    hipMemsetAsync(deg, 0, (size_t)N_NODES * sizeof(int), stream);

    // CSR pre-pass (consumed only by aggr_kernel)
    deg_kernel<<<E_EDGES / 256, 256, 0, stream>>>(ei, deg);
    scan_kernel<<<1, 1024, 0, stream>>>(deg, start, cursor);
    perm_kernel<<<E_EDGES / 256, 256, 0, stream>>>(ei, cursor, perm);

    prep_kernel<<<210, 256, 0, stream>>>(kW0, kW1, kW2, vW0, vW1, vW2, oW0, oW1, oW2, wts);

    edge_kernel<<<E_EDGES / 64, 256, 0, stream>>>(
        x, ea, ei, q,
        kb0, kb1, kb2, vb0, vb1, vb2,
        kW0t, kW1t, kW2t, vW0t, vW1t, vW2t,
        vmsg, exmsg);

    aggr_kernel<<<(N_NODES + 3) / 4, 256, 0, stream>>>(start, cursor, perm, vmsg, exmsg, aggrf);

    node_kernel<<<(N_NODES + 63) / 64, 256, 0, stream>>>(
        x, aggrf, ob0, ob1, ob2, oW0t, oW1t, oW2t, (float*)d_out);
}

// Round 11
// 474.956 us; speedup vs baseline: 1.3217x; 1.3138x over previous
//
#include <hip/hip_runtime.h>

#define N_NODES 50000
#define E_EDGES 800000
#define D_OUT   64
#define COMB    144   // 64 + 64 + 16

typedef float  f32x4  __attribute__((ext_vector_type(4)));
typedef __bf16 bf16x8 __attribute__((ext_vector_type(8)));
typedef __bf16 bf16x4 __attribute__((ext_vector_type(4)));

// ---------------- workspace layout (bytes, 256-aligned) -------------------
// identical to round 7 (119.1MB < 122.3MB proven available)
#define WS_DEG     0           // int[N]       200,000
#define WS_START   200064      // int[N]       200,000
#define WS_CURSOR  400128      // int[N]       200,000
#define WS_WTS     600192      // bf16 wts     107,520
#define WS_PERM    707840      // int[E]     3,200,000
#define WS_MSG     3907840     // bf16[E][72] 115,200,000

#define BIG_ELEMS    (64*168)   // 10752
#define SMALL_ELEMS  (64*72)    // 4608

// ---------------------------------------------------------------------------
// prep: fp32 [K][64] weights -> bf16 transposed [64][Kpad] (zero pad)
// ---------------------------------------------------------------------------
__global__ __launch_bounds__(256) void prep_kernel(
    const float* __restrict__ kW0, const float* __restrict__ kW1, const float* __restrict__ kW2,
    const float* __restrict__ vW0, const float* __restrict__ vW1, const float* __restrict__ vW2,
    const float* __restrict__ oW0, const float* __restrict__ oW1, const float* __restrict__ oW2,
    __bf16* __restrict__ wout)
{
    const int b = blockIdx.x, tid = threadIdx.x;
    const float* src;
    __bf16* dst;
    int K, Kpad, lb;
    if (b < 42)      { src = kW0; dst = wout;             K = 144; Kpad = 168; lb = b; }
    else if (b < 84) { src = vW0; dst = wout + BIG_ELEMS; K = 144; Kpad = 168; lb = b - 42; }
    else {
        const int id = (b - 84) / 18; lb = (b - 84) % 18;
        const float* s7[7] = {kW1, kW2, vW1, vW2, oW0, oW1, oW2};
        src = s7[id]; dst = wout + 2 * BIG_ELEMS + id * SMALL_ELEMS;
        K = 64; Kpad = 72;
    }
    const int idx = lb * 256 + tid;
    const int col = idx / Kpad, k = idx % Kpad;
    dst[idx] = (k < K) ? (__bf16)src[k * 64 + col] : (__bf16)0.f;
}

// ---------------------------------------------------------------------------
// CSR pre-pass (consumed only by aggr): degree -> scan -> perm
// ---------------------------------------------------------------------------
__global__ __launch_bounds__(256) void deg_kernel(const int* __restrict__ edge_index,
                                                  int* __restrict__ deg)
{
    const int e = blockIdx.x * 256 + threadIdx.x;
    if (e < E_EDGES) atomicAdd(&deg[edge_index[E_EDGES + e]], 1);
}

__global__ __launch_bounds__(1024) void scan_kernel(const int* __restrict__ deg,
                                                    int* __restrict__ start,
                                                    int* __restrict__ cursor)
{
    __shared__ int wsum[16];
    __shared__ int carry_s;
    const int tid = threadIdx.x, lane = tid & 63, wv = tid >> 6;
    if (tid == 0) carry_s = 0;
    __syncthreads();
    for (int base = 0; base < N_NODES; base += 1024) {
        const int i = base + tid;
        const int v = (i < N_NODES) ? deg[i] : 0;
        int sc = v;
        #pragma unroll
        for (int off = 1; off < 64; off <<= 1) {
            int t = __shfl_up(sc, off);
            if (lane >= off) sc += t;
        }
        if (lane == 63) wsum[wv] = sc;
        const int c = carry_s;
        __syncthreads();
        if (wv == 0 && lane < 16) {
            int ws = wsum[lane];
            #pragma unroll
            for (int off = 1; off < 16; off <<= 1) {
                int t = __shfl_up(ws, off);
                if (lane >= off) ws += t;
            }
            wsum[lane] = ws;
        }
        __syncthreads();
        const int woff = (wv == 0) ? 0 : wsum[wv - 1];
        const int excl = c + woff + sc - v;
        if (i < N_NODES) { start[i] = excl; cursor[i] = excl; }
        __syncthreads();
        if (tid == 0) carry_s = c + wsum[15];
        __syncthreads();
    }
}

__global__ __launch_bounds__(256) void perm_kernel(const int* __restrict__ edge_index,
                                                   int* __restrict__ cursor,
                                                   int* __restrict__ perm)
{
    const int e = blockIdx.x * 256 + threadIdx.x;
    if (e < E_EDGES) {
        const int d = edge_index[E_EDGES + e];
        perm[atomicAdd(&cursor[d], 1)] = e;
    }
}

// ---------------------------------------------------------------------------
// MFMA fragment convention (both operands use the SAME contiguous k = hi*8+i
// placement, so any HW k-permutation cancels):
//   A: lane holds A[row=lane&15][k=(lane>>4)*8+i]
//   B: lane holds B[k=(lane>>4)*8+i][col=lane&15]  <- from Wt[col][k]
//   D: d[r] = D[row=(lane>>4)*4+r][col=lane&15]
// ---------------------------------------------------------------------------
__device__ __forceinline__ void gemm64(const __bf16* Arow, const __bf16* Wt,
                                       int hi, int row16, f32x4 acc[4])
{
    #pragma unroll
    for (int kc = 0; kc < 2; ++kc) {
        const bf16x8 a = *(const bf16x8*)(Arow + kc * 32 + hi * 8);
        #pragma unroll
        for (int n = 0; n < 4; ++n) {
            const bf16x8 bfr = *(const bf16x8*)(Wt + (n * 16 + row16) * 72 + kc * 32 + hi * 8);
            acc[n] = __builtin_amdgcn_mfma_f32_16x16x32_bf16(a, bfr, acc[n], 0, 0, 0);
        }
    }
}

__device__ __forceinline__ bf16x8 pack8(float4 a, float4 b) {
    bf16x8 r;
    r[0] = (__bf16)a.x; r[1] = (__bf16)a.y; r[2] = (__bf16)a.z; r[3] = (__bf16)a.w;
    r[4] = (__bf16)b.x; r[5] = (__bf16)b.y; r[6] = (__bf16)b.z; r[7] = (__bf16)b.w;
    return r;
}

// ===========================================================================
// Edge kernel: one wave per 16 edges, NATURAL order, plain stores, (256,5).
// K and V stacks computed LAYER-LOCKSTEP: (L0K,L0V) -> (L1K,L1V) ->
// (L2K,L2V). 3 dependent stages instead of 6 -- each stage has 2x
// independent MFMA+LDS work for the scheduler to overlap (latency-bound fix).
// Memory behavior identical to round 7 (fastest measured: 213MB WRITE).
// ===========================================================================
__global__ __launch_bounds__(256, 5) void edge_kernel(
    const float* __restrict__ x,
    const float* __restrict__ edge_attr,
    const int*   __restrict__ edge_index,
    const float* __restrict__ q,
    const float* __restrict__ kb0, const float* __restrict__ kb1, const float* __restrict__ kb2,
    const float* __restrict__ vb0, const float* __restrict__ vb1, const float* __restrict__ vb2,
    const __bf16* __restrict__ kW0t, const __bf16* __restrict__ kW1t, const __bf16* __restrict__ kW2t,
    const __bf16* __restrict__ vW0t, const __bf16* __restrict__ vW1t, const __bf16* __restrict__ vW2t,
    __bf16* __restrict__ msg)
{
    __shared__ __bf16 HK_s[64][72];       // wave-private 16-row stripes
    __shared__ __bf16 HV_s[64][72];

    const int tid   = threadIdx.x;
    const int lane  = tid & 63;
    const int w     = tid >> 6;
    const int row16 = lane & 15;
    const int hi    = lane >> 4;
    const int wrow  = w * 16;

    const int e0 = (blockIdx.x * 4 + w) * 16;   // wave's 16 edges
    const int er = e0 + row16;                  // this lane's A-row edge

    const int src  = edge_index[er];
    const int dstn = edge_index[E_EDGES + er];

    // ---- L0 A-fragments: direct register gather (k = kc*32 + hi*8 + i) ----
    bf16x8 af[5];
    {
        const float* xs = &x[(size_t)src * 64 + hi * 8];
        af[0] = pack8(*(const float4*)xs,        *(const float4*)(xs + 4));
        af[1] = pack8(*(const float4*)(xs + 32), *(const float4*)(xs + 36));
        const float* xd = &x[(size_t)dstn * 64 + hi * 8];
        af[2] = pack8(*(const float4*)xd,        *(const float4*)(xd + 4));
        af[3] = pack8(*(const float4*)(xd + 32), *(const float4*)(xd + 36));
        if (hi < 2) {
            const float* ep = &edge_attr[(size_t)er * 16 + hi * 8];
            af[4] = pack8(*(const float4*)ep, *(const float4*)(ep + 4));
        } else {
            #pragma unroll
            for (int i = 0; i < 8; ++i) af[4][i] = (__bf16)0.f;
        }
    }

    const __bf16* hrowK = &HK_s[wrow + row16][0];
    const __bf16* hrowV = &HV_s[wrow + row16][0];

    // ================= stage 1: L0 for BOTH stacks (af dies after) ========
    float h0K[4][4], h0V[4][4];
    {
        f32x4 aK[4] = {{0,0,0,0},{0,0,0,0},{0,0,0,0},{0,0,0,0}};
        f32x4 aV[4] = {{0,0,0,0},{0,0,0,0},{0,0,0,0},{0,0,0,0}};
        #pragma unroll
        for (int kc = 0; kc < 5; ++kc) {
            #pragma unroll
            for (int n = 0; n < 4; ++n) {
                const bf16x8 bK = *(const bf16x8*)(kW0t + (n * 16 + row16) * 168 + kc * 32 + hi * 8);
                aK[n] = __builtin_amdgcn_mfma_f32_16x16x32_bf16(af[kc], bK, aK[n], 0, 0, 0);
                const bf16x8 bV = *(const bf16x8*)(vW0t + (n * 16 + row16) * 168 + kc * 32 + hi * 8);
                aV[n] = __builtin_amdgcn_mfma_f32_16x16x32_bf16(af[kc], bV, aV[n], 0, 0, 0);
            }
        }
        #pragma unroll
        for (int n = 0; n < 4; ++n) {
            const float bK = kb0[n * 16 + row16];
            const float bV = vb0[n * 16 + row16];
            #pragma unroll
            for (int r = 0; r < 4; ++r) {
                h0K[n][r] = fmaxf(aK[n][r] + bK, 0.f);
                h0V[n][r] = fmaxf(aV[n][r] + bV, 0.f);
                HK_s[wrow + hi * 4 + r][n * 16 + row16] = (__bf16)h0K[n][r];
                HV_s[wrow + hi * 4 + r][n * 16 + row16] = (__bf16)h0V[n][r];
            }
        }
    }
    __builtin_amdgcn_wave_barrier();

    // ================= stage 2: L1 for BOTH stacks ========================
    float h1K[4][4], h1V[4][4];
    {
        f32x4 cK[4] = {{0,0,0,0},{0,0,0,0},{0,0,0,0},{0,0,0,0}};
        f32x4 cV[4] = {{0,0,0,0},{0,0,0,0},{0,0,0,0},{0,0,0,0}};
        gemm64(hrowK, kW1t, hi, row16, cK);
        gemm64(hrowV, vW1t, hi, row16, cV);
        #pragma unroll
        for (int n = 0; n < 4; ++n) {
            const float bK = kb1[n * 16 + row16];
            const float bV = vb1[n * 16 + row16];
            #pragma unroll
            for (int r = 0; r < 4; ++r) {
                h1K[n][r] = fmaxf(h0K[n][r] + cK[n][r] + bK, 0.f);
                h1V[n][r] = fmaxf(h0V[n][r] + cV[n][r] + bV, 0.f);
                HK_s[wrow + hi * 4 + r][n * 16 + row16] = (__bf16)h1K[n][r];
                HV_s[wrow + hi * 4 + r][n * 16 + row16] = (__bf16)h1V[n][r];
            }
        }
    }
    __builtin_amdgcn_wave_barrier();

    // ================= stage 3: L2 both + softmax + store =================
    {
        f32x4 cK[4] = {{0,0,0,0},{0,0,0,0},{0,0,0,0},{0,0,0,0}};
        f32x4 cV[4] = {{0,0,0,0},{0,0,0,0},{0,0,0,0},{0,0,0,0}};
        gemm64(hrowK, kW2t, hi, row16, cK);
        gemm64(hrowV, vW2t, hi, row16, cV);

        float ex[4][4], vv[4][4];
        #pragma unroll
        for (int n = 0; n < 4; ++n) {
            const float bK = kb2[n * 16 + row16];
            const float bV = vb2[n * 16 + row16];
            const float qv = q[n * 16 + row16];
            #pragma unroll
            for (int r = 0; r < 4; ++r) {
                const float kk = h1K[n][r] + cK[n][r] + bK;
                vv[n][r] = h1V[n][r] + cV[n][r] + bV;
                float p2 = qv * kk;
                p2 += __shfl_xor(p2, 1);
                p2 += __shfl_xor(p2, 2);
                p2 += __shfl_xor(p2, 4);
                ex[n][r] = __expf(p2 * 0.35355339059327373f); // shift-free softmax: scores O(1)
            }
        }

        // message store: natural slot, sequential, PLAIN stores (round-7)
        #pragma unroll
        for (int r = 0; r < 4; ++r) {
            __bf16* mrow = msg + (size_t)(e0 + hi * 4 + r) * 72;
            #pragma unroll
            for (int n = 0; n < 4; ++n)
                mrow[n * 16 + row16] = (__bf16)(ex[n][r] * vv[n][r]);
            if ((row16 & 7) == 0) {                  // row16 in {0,8}
                #pragma unroll
                for (int n = 0; n < 4; ++n)
                    mrow[64 + 2 * n + (row16 >> 3)] = (__bf16)ex[n][r];
            }
        }
    }
}

// ---------------------------------------------------------------------------
// Aggregation: wave per node, 4 edges/iter via 4x16-lane groups (perm
// gather into the natural-order msg). Lane (g,l) loads bf16x4 of channels
// l*4.. from its group's row + ex of head l/2; 2 shfl_xor combine groups;
// g==0 lanes write float4 into d_out scratch.
// ---------------------------------------------------------------------------
__global__ __launch_bounds__(256, 8) void aggr_kernel(
    const int* __restrict__ start, const int* __restrict__ endc,
    const int* __restrict__ perm, const __bf16* __restrict__ msg,
    float* __restrict__ aggr_out)
{
    const int lane = threadIdx.x & 63;
    const int n    = blockIdx.x * 4 + (threadIdx.x >> 6);
    if (n >= N_NODES) return;
    const int g = lane >> 4;          // edge-group 0..3
    const int l = lane & 15;          // channel slice l*4..l*4+3, head l/2
    const int s0 = start[n], e1 = endc[n];   // cursor-after-perm == start[n+1]

    float m0 = 0.f, m1 = 0.f, m2 = 0.f, m3 = 0.f, ae = 0.f;
    for (int i = s0 + g; i < e1; i += 4) {
        const size_t b0 = (size_t)perm[i] * 72;
        const bf16x4 v = *(const bf16x4*)&msg[b0 + l * 4];
        ae += (float)msg[b0 + 64 + (l >> 1)];
        m0 += (float)v[0]; m1 += (float)v[1]; m2 += (float)v[2]; m3 += (float)v[3];
    }
    #pragma unroll
    for (int m = 16; m < 64; m <<= 1) {
        m0 += __shfl_xor(m0, m); m1 += __shfl_xor(m1, m);
        m2 += __shfl_xor(m2, m); m3 += __shfl_xor(m3, m);
        ae += __shfl_xor(ae, m);
    }
    if (g == 0) {
        const float inv = (ae > 0.f) ? 1.f / ae : 0.f;
        float4 o;
        o.x = fmaxf(m0 * inv, 0.f);
        o.y = fmaxf(m1 * inv, 0.f);
        o.z = fmaxf(m2 * inv, 0.f);
        o.w = fmaxf(m3 * inv, 0.f);
        *(float4*)&aggr_out[(size_t)n * 64 + l * 4] = o;
    }
}

// ---------------------------------------------------------------------------
// Node kernel: stages f32 aggr (from d_out scratch) into LDS, runs out
// stack, overwrites d_out with the final result. Per-block read==write rows.
// ---------------------------------------------------------------------------
__global__ __launch_bounds__(256) void node_kernel(
    const float* __restrict__ x, const float* __restrict__ aggr_in,
    const float* __restrict__ ob0, const float* __restrict__ ob1, const float* __restrict__ ob2,
    const __bf16* __restrict__ oW0t, const __bf16* __restrict__ oW1t, const __bf16* __restrict__ oW2t,
    float* __restrict__ out)
{
    __shared__ __bf16 A_s[64][72];
    __shared__ __bf16 H_s[64][72];

    const int tid  = threadIdx.x;
    const int lane = tid & 63;
    const int w    = tid >> 6;
    const int n0   = blockIdx.x * 64;
    const int row16 = lane & 15;
    const int hi    = lane >> 4;

    {   // stage aggr rows (f32 -> bf16)
        const int r = tid >> 2, seg = tid & 3;       // 64 rows x 4 segs x 16
        const int node = n0 + r;
        #pragma unroll
        for (int gg = 0; gg < 4; ++gg) {
            bf16x4 h; h[0] = h[1] = h[2] = h[3] = (__bf16)0.f;
            if (node < N_NODES) {
                const float4 f = *(const float4*)&aggr_in[(size_t)node * 64 + seg * 16 + gg * 4];
                h[0] = (__bf16)f.x; h[1] = (__bf16)f.y; h[2] = (__bf16)f.z; h[3] = (__bf16)f.w;
            }
            *(bf16x4*)&A_s[r][seg * 16 + gg * 4] = h;
        }
    }
    __syncthreads();

    const __bf16* arow = &A_s[w * 16 + row16][0];
    const __bf16* hrow = &H_s[w * 16 + row16][0];

    f32x4 acc[4] = {{0,0,0,0},{0,0,0,0},{0,0,0,0},{0,0,0,0}};
    gemm64(arow, oW0t, hi, row16, acc);
    float h0[4][4];
    #pragma unroll
    for (int n = 0; n < 4; ++n) {
        const float bias = ob0[n * 16 + row16];
        #pragma unroll
        for (int r = 0; r < 4; ++r) {
            h0[n][r] = fmaxf(acc[n][r] + bias, 0.f);
            H_s[w * 16 + hi * 4 + r][n * 16 + row16] = (__bf16)h0[n][r];
        }
    }
    __builtin_amdgcn_wave_barrier();

    f32x4 acc1[4] = {{0,0,0,0},{0,0,0,0},{0,0,0,0},{0,0,0,0}};
    gemm64(hrow, oW1t, hi, row16, acc1);
    float h1[4][4];
    #pragma unroll
    for (int n = 0; n < 4; ++n) {
        const float bias = ob1[n * 16 + row16];
        #pragma unroll
        for (int r = 0; r < 4; ++r) {
            h1[n][r] = fmaxf(h0[n][r] + acc1[n][r] + bias, 0.f);
            H_s[w * 16 + hi * 4 + r][n * 16 + row16] = (__bf16)h1[n][r];
        }
    }
    __builtin_amdgcn_wave_barrier();

    f32x4 acc2[4] = {{0,0,0,0},{0,0,0,0},{0,0,0,0},{0,0,0,0}};
    gemm64(hrow, oW2t, hi, row16, acc2);
    #pragma unroll
    for (int n = 0; n < 4; ++n) {
        const float bias = ob2[n * 16 + row16];
        #pragma unroll
        for (int r = 0; r < 4; ++r) {
            const int node = n0 + w * 16 + hi * 4 + r;
            if (node < N_NODES) {
                const int col = n * 16 + row16;
                const float o = h1[n][r] + acc2[n][r] + bias;
                out[(size_t)node * 64 + col] = fmaxf(x[(size_t)node * 64 + col] + o, 0.f);
            }
        }
    }
}

extern "C" void kernel_launch(void* const* d_in, const int* in_sizes, int n_in,
                              void* d_out, int out_size, void* d_ws, size_t ws_size,
                              hipStream_t stream) {
    const float* x  = (const float*)d_in[0];
    const float* ea = (const float*)d_in[1];
    const int*   ei = (const int*)d_in[2];
    const float* q  = (const float*)d_in[3];
    const float* kW0 = (const float*)d_in[4];  const float* kb0 = (const float*)d_in[5];
    const float* kW1 = (const float*)d_in[6];  const float* kb1 = (const float*)d_in[7];
    const float* kW2 = (const float*)d_in[8];  const float* kb2 = (const float*)d_in[9];
    const float* vW0 = (const float*)d_in[10]; const float* vb0 = (const float*)d_in[11];
    const float* vW1 = (const float*)d_in[12]; const float* vb1 = (const float*)d_in[13];
    const float* vW2 = (const float*)d_in[14]; const float* vb2 = (const float*)d_in[15];
    const float* oW0 = (const float*)d_in[16]; const float* ob0 = (const float*)d_in[17];
    const float* oW1 = (const float*)d_in[18]; const float* ob1 = (const float*)d_in[19];
    const float* oW2 = (const float*)d_in[20]; const float* ob2 = (const float*)d_in[21];

    char* ws = (char*)d_ws;
    int*    deg    = (int*)(ws + WS_DEG);
    int*    start  = (int*)(ws + WS_START);
    int*    cursor = (int*)(ws + WS_CURSOR);
    __bf16* wts    = (__bf16*)(ws + WS_WTS);
    int*    perm   = (int*)(ws + WS_PERM);
    __bf16* msg    = (__bf16*)(ws + WS_MSG);
    float*  aggrf  = (float*)d_out;              // d_out doubles as scratch

    __bf16* kW0t = wts;
    __bf16* vW0t = wts + BIG_ELEMS;
    __bf16* sm   = wts + 2 * BIG_ELEMS;
    __bf16* kW1t = sm;                   __bf16* kW2t = sm + SMALL_ELEMS;
    __bf16* vW1t = sm + 2 * SMALL_ELEMS; __bf16* vW2t = sm + 3 * SMALL_ELEMS;
    __bf16* oW0t = sm + 4 * SMALL_ELEMS; __bf16* oW1t = sm + 5 * SMALL_ELEMS;
    __bf16* oW2t = sm + 6 * SMALL_ELEMS;

    hipMemsetAsync(deg, 0, (size_t)N_NODES * sizeof(int), stream);

    // CSR pre-pass (consumed only by aggr_kernel)
    deg_kernel<<<E_EDGES / 256, 256, 0, stream>>>(ei, deg);
    scan_kernel<<<1, 1024, 0, stream>>>(deg, start, cursor);
    perm_kernel<<<E_EDGES / 256, 256, 0, stream>>>(ei, cursor, perm);

    prep_kernel<<<210, 256, 0, stream>>>(kW0, kW1, kW2, vW0, vW1, vW2, oW0, oW1, oW2, wts);

    edge_kernel<<<E_EDGES / 64, 256, 0, stream>>>(
        x, ea, ei, q,
        kb0, kb1, kb2, vb0, vb1, vb2,
        kW0t, kW1t, kW2t, vW0t, vW1t, vW2t,
        msg);

    aggr_kernel<<<(N_NODES + 3) / 4, 256, 0, stream>>>(start, cursor, perm, msg, aggrf);

    node_kernel<<<(N_NODES + 63) / 64, 256, 0, stream>>>(
        x, aggrf, ob0, ob1, ob2, oW0t, oW1t, oW2t, (float*)d_out);
}